// Round 5
// baseline (383.389 us; speedup 1.0000x reference)
//
#include <hip/hip_runtime.h>
#include <stdint.h>

#define BATCH 16
#define HW (1024*1024)           // pixels per batch image
#define NPIX (BATCH * HW)        // 16,777,216 total pixels
#define SBLK 64                  // blocks per batch in scan kernel

typedef float vf4 __attribute__((ext_vector_type(4)));   // native vec4 for NT builtins

// Per-batch merged state (all fields valid with zero-init):
//   valid : any pixel with integral mi in [0,255]
//   maxp1 : max occupied bin + 1          (0 = no in-range pixel)
//   maxc  : max (256 - occupied bin)      (0 = no in-range pixel)
//   done  : early-exit latch
// flag = valid && (maxp1 + maxc > 257)  [since maxp1+maxc = 257 + (max-min)]
// Monotone under more data -> early exit is exact, not approximate.
struct BState { unsigned valid, maxp1, maxc, done; };

// ---------------------------------------------------------------------------
// Kernel 1: early-exiting scan. Each block owns 16384 floats of one batch,
// processed in 16 chunks of 256 float4; after each chunk it merges partials
// into device-scope atomics and checks the per-batch done latch.
// ---------------------------------------------------------------------------
__global__ __launch_bounds__(256) void scan_kernel(const float* __restrict__ in,
                                                   BState* __restrict__ st) {
    const int tid = threadIdx.x;
    const int batch = blockIdx.y;
    BState* s = st + batch;
    const vf4* src = (const vf4*)(in + (size_t)batch * HW) + (size_t)blockIdx.x * 4096;
    __shared__ int sdone;

    for (int c = 0; c < 16; ++c) {
        if (tid == 0)
            sdone = (int)__hip_atomic_load(&s->done, __ATOMIC_RELAXED, __HIP_MEMORY_SCOPE_AGENT);
        __syncthreads();
        if (sdone) return;

        vf4 x = src[c * 256 + tid];
        int minb = 0x7FFF, maxb = -1, valid = 0;
        float v[4] = {x.x, x.y, x.z, x.w};
#pragma unroll
        for (int k = 0; k < 4; ++k) {
            float mi = v[k] * 255.0f;                 // replicate reference arithmetic
            if (mi >= 0.0f && mi <= 255.0f) {         // histogram range, edges inclusive
                int b = (int)(mi * (256.0f / 255.0f));
                if (b > 255) b = 255;                 // right edge -> last bin
                minb = min(minb, b);
                maxb = max(maxb, b);
                valid |= (mi == rintf(mi)) ? 1 : 0;   // round-half-even == jnp.round
            }
        }
        // 64-lane butterfly reduce within each wave
#pragma unroll
        for (int off = 32; off > 0; off >>= 1) {
            minb  = min(minb, __shfl_xor(minb, off));
            maxb  = max(maxb, __shfl_xor(maxb, off));
            valid |= __shfl_xor(valid, off);
        }
        if ((tid & 63) == 0) {                        // one lane per wave merges
            if (maxb >= 0) {
                atomicMax(&s->maxp1, (unsigned)(maxb + 1));
                atomicMax(&s->maxc,  (unsigned)(256 - minb));
            }
            if (valid) atomicOr(&s->valid, 1u);
        }
        __syncthreads();                              // all 4 waves merged; also guards sdone reuse
        if (tid == 0) {
            unsigned v2 = __hip_atomic_load(&s->valid, __ATOMIC_RELAXED, __HIP_MEMORY_SCOPE_AGENT);
            unsigned mp = __hip_atomic_load(&s->maxp1, __ATOMIC_RELAXED, __HIP_MEMORY_SCOPE_AGENT);
            unsigned mc = __hip_atomic_load(&s->maxc,  __ATOMIC_RELAXED, __HIP_MEMORY_SCOPE_AGENT);
            if (v2 && (mp + mc > 257))
                __hip_atomic_store(&s->done, 1u, __ATOMIC_RELAXED, __HIP_MEMORY_SCOPE_AGENT);
        }
    }
}

// ---------------------------------------------------------------------------
// Kernel 2: fused mask-apply + 2-way softmax (sigmoid form), vec4 + NT mem.
// m = flag ? (x*255)/255 : 0 ; o0 = 1/(1+e^{1-2m}) ; o1 = e * o0.
// Output layout: [msks0 (16M floats) | msks1 (16M floats)].
// ---------------------------------------------------------------------------
__device__ __forceinline__ float2 softmax2(float x, float fm) {
    float mi = x * 255.0f;
    float m = (mi / 255.0f) * fm;          // fm in {0,1}: masked or zeroed
    float e = expf(1.0f - 2.0f * m);       // e^{b-a}, b-a = (1-m)-m
    float r = 1.0f / (1.0f + e);
    return make_float2(r, e * r);          // (e^a, e^b) / (e^a+e^b)
}

__global__ __launch_bounds__(256) void out_kernel(const float* __restrict__ in,
                                                  const BState* __restrict__ st,
                                                  float* __restrict__ out) {
    const int batch = blockIdx.x >> 10;    // 1024 blocks per batch image (uniform -> scalar)
    const BState s = st[batch];            // visible: kernel-boundary ordering
    const float fm = (s.valid && (s.maxp1 + s.maxc > 257)) ? 1.0f : 0.0f;
    const size_t i4 = (size_t)blockIdx.x * 256 + threadIdx.x;
    vf4 x = __builtin_nontemporal_load(&((const vf4*)in)[i4]);
    float2 rx = softmax2(x.x, fm);
    float2 ry = softmax2(x.y, fm);
    float2 rz = softmax2(x.z, fm);
    float2 rw = softmax2(x.w, fm);
    vf4 o0 = {rx.x, ry.x, rz.x, rw.x};
    vf4 o1 = {rx.y, ry.y, rz.y, rw.y};
    __builtin_nontemporal_store(o0, &((vf4*)out)[i4]);
    __builtin_nontemporal_store(o1, &((vf4*)(out + (size_t)NPIX))[i4]);
}

// ---------------------------------------------------------------------------
extern "C" void kernel_launch(void* const* d_in, const int* in_sizes, int n_in,
                              void* d_out, int out_size, void* d_ws, size_t ws_size,
                              hipStream_t stream) {
    const float* irr = (const float*)d_in[0];
    // d_in[1] (image_vis) is unused by the reference's outputs.
    float* out = (float*)d_out;
    BState* st = (BState*)d_ws;

    (void)hipMemsetAsync(st, 0, BATCH * sizeof(BState), stream);   // 256 B, init latches
    scan_kernel<<<dim3(SBLK, BATCH), 256, 0, stream>>>(irr, st);
    out_kernel<<<NPIX / 4 / 256, 256, 0, stream>>>(irr, st, out);
}

// Round 6
// 224.912 us; speedup vs baseline: 1.7046x; 1.7046x over previous
//
#include <hip/hip_runtime.h>
#include <stdint.h>

#define BATCH 16
#define HW (1024*1024)           // pixels per batch image
#define NPIX (BATCH * HW)        // 16,777,216 total pixels
#define SBLK 64                  // blocks per batch in scan kernel

typedef float vf4 __attribute__((ext_vector_type(4)));   // native vec4 for NT builtins

// ---------------------------------------------------------------------------
// Kernel 1: streaming reduction, contention-free (per-block partial stores).
//   minb  = min occupied histogram bin (0x7FFF if none in-range)
//   maxb  = max occupied histogram bin (-1 if none)
//   valid = any pixel with integral mi in [0,255]
// mask.max()>0  <=>  (any valid pixel) AND (min occupied bin != max occupied
// bin): for a valid pixel mi=n (integer 0..255) its bin index equals n, so
// sum_k |n-k| hist[k] > 0 iff another bin is occupied (all terms are
// non-negative integers -> no fp cancellation in the reference matvec).
// ---------------------------------------------------------------------------
__global__ __launch_bounds__(256) void scan_kernel(const float* __restrict__ in,
                                                   uint2* __restrict__ partials) {
    const int tid = threadIdx.x;
    const int batch = blockIdx.y;
    int minb = 0x7FFF, maxb = -1, valid = 0;

    // each block: 4096 float4 = 16384 floats of one batch image
    const vf4* src = (const vf4*)(in + (size_t)batch * HW) + (size_t)blockIdx.x * 4096;
    for (int i = tid; i < 4096; i += 256) {
        vf4 x = __builtin_nontemporal_load(&src[i]);
        float v[4] = {x.x, x.y, x.z, x.w};
#pragma unroll
        for (int k = 0; k < 4; ++k) {
            float mi = v[k] * 255.0f;                 // replicate reference arithmetic
            if (mi >= 0.0f && mi <= 255.0f) {         // histogram range, edges inclusive
                int b = (int)(mi * (256.0f / 255.0f));
                if (b > 255) b = 255;                 // right edge -> last bin
                minb = min(minb, b);
                maxb = max(maxb, b);
                valid |= (mi == rintf(mi)) ? 1 : 0;   // round-half-even == jnp.round
            }
        }
    }
    // 64-lane butterfly reduce within each wave
#pragma unroll
    for (int off = 32; off > 0; off >>= 1) {
        minb  = min(minb, __shfl_xor(minb, off));
        maxb  = max(maxb, __shfl_xor(maxb, off));
        valid |= __shfl_xor(valid, off);
    }
    // cross-wave reduce via LDS (4 waves)
    __shared__ int sm[4], sx[4], sv[4];
    const int w = tid >> 6;
    if ((tid & 63) == 0) { sm[w] = minb; sx[w] = maxb; sv[w] = valid; }
    __syncthreads();
    if (tid == 0) {
#pragma unroll
        for (int i = 1; i < 4; ++i) {
            minb  = min(minb, sm[i]);
            maxb  = max(maxb, sx[i]);
            valid |= sv[i];
        }
        uint2 p;
        p.x = ((unsigned)(minb & 0xFFFF) << 16) | (unsigned)(maxb & 0xFFFF);
        p.y = (unsigned)valid;
        partials[batch * SBLK + blockIdx.x] = p;
    }
}

// ---------------------------------------------------------------------------
// Kernel 2: combine 64 per-block partials per batch -> flag. One wave/batch.
// ---------------------------------------------------------------------------
__global__ __launch_bounds__(64) void flag_kernel(const uint2* __restrict__ partials,
                                                  unsigned* __restrict__ flags) {
    const int b = blockIdx.x;
    const int t = threadIdx.x;
    uint2 p = partials[b * SBLK + t];
    int minb = (int)(short)(p.x >> 16);     // sign-extend: 0x7FFF stays, maxb -1 stays
    int maxb = (int)(short)(p.x & 0xFFFF);
    unsigned valid = p.y;
#pragma unroll
    for (int off = 32; off > 0; off >>= 1) {
        minb = min(minb, __shfl_xor(minb, off));
        maxb = max(maxb, __shfl_xor(maxb, off));
        valid |= (unsigned)__shfl_xor((int)valid, off);
    }
    if (t == 0) flags[b] = (valid && (minb != maxb)) ? 1u : 0u;
}

// ---------------------------------------------------------------------------
// Kernel 3: fused mask-apply + 2-way softmax (sigmoid form), vec4 + NT mem.
// m = flag ? (x*255)/255 : 0 ; o0 = 1/(1+e^{1-2m}) ; o1 = e * o0.
// Output layout: [msks0 (16M floats) | msks1 (16M floats)].
// ---------------------------------------------------------------------------
__device__ __forceinline__ float2 softmax2(float x, float fm) {
    float mi = x * 255.0f;
    float m = (mi / 255.0f) * fm;          // fm in {0,1}: masked or zeroed
    float e = expf(1.0f - 2.0f * m);       // e^{b-a}, b-a = (1-m)-m
    float r = 1.0f / (1.0f + e);
    return make_float2(r, e * r);          // (e^a, e^b) / (e^a+e^b)
}

__global__ __launch_bounds__(256) void out_kernel(const float* __restrict__ in,
                                                  const unsigned* __restrict__ flags,
                                                  float* __restrict__ out) {
    const int batch = blockIdx.x >> 10;    // 1024 blocks per batch image (uniform -> scalar)
    const float fm = flags[batch] ? 1.0f : 0.0f;
    const size_t i4 = (size_t)blockIdx.x * 256 + threadIdx.x;
    vf4 x = __builtin_nontemporal_load(&((const vf4*)in)[i4]);
    float2 rx = softmax2(x.x, fm);
    float2 ry = softmax2(x.y, fm);
    float2 rz = softmax2(x.z, fm);
    float2 rw = softmax2(x.w, fm);
    vf4 o0 = {rx.x, ry.x, rz.x, rw.x};
    vf4 o1 = {rx.y, ry.y, rz.y, rw.y};
    __builtin_nontemporal_store(o0, &((vf4*)out)[i4]);
    __builtin_nontemporal_store(o1, &((vf4*)(out + (size_t)NPIX))[i4]);
}

// ---------------------------------------------------------------------------
extern "C" void kernel_launch(void* const* d_in, const int* in_sizes, int n_in,
                              void* d_out, int out_size, void* d_ws, size_t ws_size,
                              hipStream_t stream) {
    const float* irr = (const float*)d_in[0];
    // d_in[1] (image_vis) is unused by the reference's outputs.
    float* out = (float*)d_out;

    uint2* partials = (uint2*)d_ws;                      // 16*64 uint2 = 8 KB
    unsigned* flags = (unsigned*)(partials + BATCH * SBLK);
    // No memset needed: partials fully written by scan_kernel, flags by flag_kernel.

    scan_kernel<<<dim3(SBLK, BATCH), 256, 0, stream>>>(irr, partials);
    flag_kernel<<<BATCH, 64, 0, stream>>>(partials, flags);
    out_kernel<<<NPIX / 4 / 256, 256, 0, stream>>>(irr, flags, out);
}